// Round 4
// baseline (116.004 us; speedup 1.0000x reference)
//
#include <hip/hip_runtime.h>

// SplineActivation: out = sum_n Bspline3_n(clip(x,-2,2)) * coeffs[n]
// Uniform knots linspace(-2,2,14), h = 4/13. Closed-form per-interval cubic:
//   s = clamp((x+2)*13/4, 0, 13); i = min(floor(s),12); t = s - i
//   out = A[i] + B[i]t + G[i]t^2 + D[i]t^3
// Special case (reference's .at[-1].add(xc==2)): x >= 2 (s==13) -> coeffs[9].
//
// R3 probe: 4 independent float4 loads in flight per thread (MLP/ILP probe
// to falsify "grid-stride loop is latency-bound" hypothesis).

#define NSPL 10

__device__ __forceinline__ float spline_eval(
    float xv, const float* sA, const float* sB, const float* sG,
    const float* sD, float c9)
{
    float s = fmaf(xv, 3.25f, 6.5f);            // (x+2)*13/4, clip folded in
    s = fminf(fmaxf(s, 0.0f), 13.0f);           // v_med3_f32
    int ii = (int)s;
    ii = ii > 12 ? 12 : ii;
    float t = s - (float)ii;
    float res = fmaf(fmaf(fmaf(sD[ii], t, sG[ii]), t, sB[ii]), t, sA[ii]);
    return (s >= 13.0f) ? c9 : res;             // x>=2 special case
}

__global__ __launch_bounds__(256) void spline_act_kernel(
    const float* __restrict__ x,
    const float* __restrict__ coeffs,
    float* __restrict__ out,
    int n4, int n)
{
    // Four separate 16-float arrays: each spans 16 LDS banks -> conflict-free.
    __shared__ float sA[16], sB[16], sG[16], sD[16];

    const int tid = threadIdx.x;
    if (tid < 16) {
        int j0 = tid - 3, j1 = tid - 2, j2 = tid - 1, j3 = tid;
        float c0 = (j0 >= 0 && j0 < NSPL) ? coeffs[j0] : 0.0f;
        float c1 = (j1 >= 0 && j1 < NSPL) ? coeffs[j1] : 0.0f;
        float c2 = (j2 >= 0 && j2 < NSPL) ? coeffs[j2] : 0.0f;
        float c3 = (j3 >= 0 && j3 < NSPL) ? coeffs[j3] : 0.0f;
        sA[tid] = (c0 + 4.0f * c1 + c2) * (1.0f / 6.0f);
        sB[tid] = (c2 - c0) * 0.5f;
        sG[tid] = (c0 - 2.0f * c1 + c2) * 0.5f;
        sD[tid] = (c3 - c0 + 3.0f * (c1 - c2)) * (1.0f / 6.0f);
    }
    __syncthreads();

    const float c9 = coeffs[9];

    const int gid = blockIdx.x * blockDim.x + tid;
    const int tpg = gridDim.x * blockDim.x;     // total threads

    const float4* __restrict__ x4 = reinterpret_cast<const float4*>(x);
    float4* __restrict__ o4 = reinterpret_cast<float4*>(out);

    int i = gid;
    // Batches of 4: all four loads independent, issued before any compute.
    // Bench shape: n4 = 4*tpg exactly -> every thread runs exactly one batch.
    for (; i + 3 * tpg < n4; i += 4 * tpg) {
        float4 v0 = x4[i];
        float4 v1 = x4[i + tpg];
        float4 v2 = x4[i + 2 * tpg];
        float4 v3 = x4[i + 3 * tpg];
        float4 r0, r1, r2, r3;
#pragma unroll
        for (int k = 0; k < 4; ++k) {
            (&r0.x)[k] = spline_eval((&v0.x)[k], sA, sB, sG, sD, c9);
            (&r1.x)[k] = spline_eval((&v1.x)[k], sA, sB, sG, sD, c9);
            (&r2.x)[k] = spline_eval((&v2.x)[k], sA, sB, sG, sD, c9);
            (&r3.x)[k] = spline_eval((&v3.x)[k], sA, sB, sG, sD, c9);
        }
        o4[i] = r0;
        o4[i + tpg] = r1;
        o4[i + 2 * tpg] = r2;
        o4[i + 3 * tpg] = r3;
    }
    // Remainder float4s
    for (; i < n4; i += tpg) {
        float4 v = x4[i];
        float4 r;
#pragma unroll
        for (int k = 0; k < 4; ++k)
            (&r.x)[k] = spline_eval((&v.x)[k], sA, sB, sG, sD, c9);
        o4[i] = r;
    }
    // Scalar tail (n % 4)
    for (int idx = n4 * 4 + gid; idx < n; idx += tpg)
        out[idx] = spline_eval(x[idx], sA, sB, sG, sD, c9);
}

extern "C" void kernel_launch(void* const* d_in, const int* in_sizes, int n_in,
                              void* d_out, int out_size, void* d_ws, size_t ws_size,
                              hipStream_t stream) {
    const float* x = (const float*)d_in[0];
    const float* coeffs = (const float*)d_in[1];
    float* out = (float*)d_out;

    const int n = in_sizes[0];
    const int n4 = n >> 2;

    const int block = 256;
    // One 4-float4 batch per thread: grid = ceil(n4 / (block*4)).
    long long g = ((long long)n4 + block * 4 - 1) / (block * 4);
    int grid = (int)(g < 1 ? 1 : (g > 8192 ? 8192 : g));

    spline_act_kernel<<<grid, block, 0, stream>>>(x, coeffs, out, n4, n);
}

// Round 5
// 112.962 us; speedup vs baseline: 1.0269x; 1.0269x over previous
//
#include <hip/hip_runtime.h>

// SplineActivation: out = sum_n Bspline3_n(clip(x,-2,2)) * coeffs[n]
// Uniform knots linspace(-2,2,14), h = 4/13. Closed-form per-interval cubic:
//   s = clamp((x+2)*13/4, 0, 13); i = min(floor(s),12); t = s - i
//   out = A[i] + B[i]t + G[i]t^2 + D[i]t^3
// Special case (reference's .at[-1].add(xc==2)): x >= 2 (s==13) -> coeffs[9].
//
// FINAL (R2 structure, best measured 112.9 us):
//   - memory-bound elementwise map: 64 MB in + 64 MB out mandatory HBM traffic
//     (ws re-poison flushes L3 between replays). Floor ~20 us @ 6.4 TB/s.
//   - R4 probe showed 4-deep ILP batching is neutral (TLP already saturates
//     the memory pipe); grid-stride + unroll(2) is optimal.
//   - 4x16 LDS tables: conflict-free gather (16 banks/array, broadcast dups).

#define NSPL 10

__global__ __launch_bounds__(256) void spline_act_kernel(
    const float* __restrict__ x,
    const float* __restrict__ coeffs,
    float* __restrict__ out,
    int n4, int n)
{
    __shared__ float sA[16], sB[16], sG[16], sD[16];

    const int tid = threadIdx.x;
    if (tid < 16) {
        // Padded coeff fetch: c[j] = coeffs[j] if 0<=j<10 else 0
        int j0 = tid - 3, j1 = tid - 2, j2 = tid - 1, j3 = tid;
        float c0 = (j0 >= 0 && j0 < NSPL) ? coeffs[j0] : 0.0f;
        float c1 = (j1 >= 0 && j1 < NSPL) ? coeffs[j1] : 0.0f;
        float c2 = (j2 >= 0 && j2 < NSPL) ? coeffs[j2] : 0.0f;
        float c3 = (j3 >= 0 && j3 < NSPL) ? coeffs[j3] : 0.0f;
        // Uniform cubic B-spline blending, collected by powers of t:
        sA[tid] = (c0 + 4.0f * c1 + c2) * (1.0f / 6.0f);
        sB[tid] = (c2 - c0) * 0.5f;
        sG[tid] = (c0 - 2.0f * c1 + c2) * 0.5f;
        sD[tid] = (c3 - c0 + 3.0f * (c1 - c2)) * (1.0f / 6.0f);
    }
    __syncthreads();

    const float c9 = coeffs[9];

    const int gid = blockIdx.x * blockDim.x + tid;
    const int stride = gridDim.x * blockDim.x;

    const float4* __restrict__ x4 = reinterpret_cast<const float4*>(x);
    float4* __restrict__ o4 = reinterpret_cast<float4*>(out);

#pragma unroll 2
    for (int idx = gid; idx < n4; idx += stride) {
        float4 v = x4[idx];
        float4 r;
        float* vi = reinterpret_cast<float*>(&v);
        float* ri = reinterpret_cast<float*>(&r);
#pragma unroll
        for (int k = 0; k < 4; ++k) {
            float s = fmaf(vi[k], 3.25f, 6.5f);     // (x+2)*13/4, clip folded
            s = fminf(fmaxf(s, 0.0f), 13.0f);       // v_med3_f32
            int ii = (int)s;
            ii = ii > 12 ? 12 : ii;
            float t = s - (float)ii;
            float res = fmaf(fmaf(fmaf(sD[ii], t, sG[ii]), t, sB[ii]), t, sA[ii]);
            ri[k] = (s >= 13.0f) ? c9 : res;        // x>=2 special case
        }
        o4[idx] = r;
    }

    // Scalar tail (n % 4 != 0 — not hit at this shape, kept for safety)
    for (int idx = n4 * 4 + gid; idx < n; idx += stride) {
        float s = fmaf(x[idx], 3.25f, 6.5f);
        s = fminf(fmaxf(s, 0.0f), 13.0f);
        int ii = (int)s;
        ii = ii > 12 ? 12 : ii;
        float t = s - (float)ii;
        float res = fmaf(fmaf(fmaf(sD[ii], t, sG[ii]), t, sB[ii]), t, sA[ii]);
        out[idx] = (s >= 13.0f) ? c9 : res;
    }
}

extern "C" void kernel_launch(void* const* d_in, const int* in_sizes, int n_in,
                              void* d_out, int out_size, void* d_ws, size_t ws_size,
                              hipStream_t stream) {
    const float* x = (const float*)d_in[0];
    const float* coeffs = (const float*)d_in[1];
    float* out = (float*)d_out;

    const int n = in_sizes[0];
    const int n4 = n >> 2;

    const int block = 256;
    int grid = (n4 + block - 1) / block;
    if (grid > 2048) grid = 2048;
    if (grid < 1) grid = 1;

    spline_act_kernel<<<grid, block, 0, stream>>>(x, coeffs, out, n4, n);
}